// Round 7
// baseline (226.699 us; speedup 1.0000x reference)
//
#include <hip/hip_runtime.h>

typedef unsigned short u16;
typedef __attribute__((ext_vector_type(8))) short bf16x8;
typedef __attribute__((ext_vector_type(4))) float f32x4;

#define B_DIM 4096
#define D_DIM 512
#define H_DIM 16

typedef const __attribute__((address_space(1))) unsigned int* gas_t;
typedef __attribute__((address_space(3))) unsigned int* las_t;

__device__ __forceinline__ u16 f2bf(float f) {
  union { float f; unsigned u; } x;
  x.f = f;
  unsigned r = x.u + 0x7FFFu + ((x.u >> 16) & 1u);
  return (u16)(r >> 16);
}

__device__ __forceinline__ uint4 pack8(float4 v0, float4 v1) {
  union { uint4 q; u16 h[8]; } u;
  u.h[0] = f2bf(v0.x); u.h[1] = f2bf(v0.y); u.h[2] = f2bf(v0.z); u.h[3] = f2bf(v0.w);
  u.h[4] = f2bf(v1.x); u.h[5] = f2bf(v1.y); u.h[6] = f2bf(v1.z); u.h[7] = f2bf(v1.w);
  return u.q;
}

// ---- prep uber kernel ----
// kind 0: transpose f32->bf16; 1: transpose with lam(conf) row-scale;
// 2: count reduction (1 block); 4: zero f32 (4096 floats/block).
struct TJob {
  const float* in;
  void* out;
  const float* conf;
  int rows, cols, tiles_x, tile_off, kind;
};
struct TJobs { TJob j[10]; };

__global__ __launch_bounds__(256) void mega_prep(TJobs J, float* __restrict__ countp) {
  __shared__ float tile[32][33];
  __shared__ float wsum[4];
  const int tid = threadIdx.x;
  int b = blockIdx.x;
  int sel = 0;
#pragma unroll
  for (int i = 1; i < 10; ++i)
    if (b >= J.j[i].tile_off) sel = i;
  TJob jb = J.j[sel];
  b -= jb.tile_off;

  if (jb.kind == 4) {  // zero f32
    long long base = (long long)b * 4096 + tid * 16;
    float4 z = {0.f, 0.f, 0.f, 0.f};
    float* o = (float*)jb.out + base;
    *(float4*)o = z; *(float4*)(o + 4) = z; *(float4*)(o + 8) = z; *(float4*)(o + 12) = z;
    return;
  }
  if (jb.kind == 2) {  // count
    float m = 0.f;
    for (int i = tid; i < B_DIM; i += 256) {
      float l = 1.0f - jb.in[i];
      l = fminf(fmaxf(l, 0.f), 1.f);
      m += (l > 0.3f) ? 1.f : 0.f;
    }
    for (int off = 32; off; off >>= 1) m += __shfl_down(m, off, 64);
    if ((tid & 63) == 0) wsum[tid >> 6] = m;
    __syncthreads();
    if (tid == 0) countp[0] = wsum[0] + wsum[1] + wsum[2] + wsum[3];
    return;
  }

  // transpose kinds 0/1
  long long c0 = (long long)(b % jb.tiles_x) * 32;
  long long r0 = (long long)(b / jb.tiles_x) * 32;
  int tx = tid & 31, ty = tid >> 5;
#pragma unroll
  for (int i = 0; i < 4; ++i) {
    int row = ty + i * 8;
    float v = jb.in[(r0 + row) * jb.cols + c0 + tx];
    if (jb.kind == 1) {
      float l = 1.0f - jb.conf[r0 + row];
      l = fminf(fmaxf(l, 0.f), 1.f);
      v *= (l > 0.3f) ? l : 0.f;
    }
    tile[row][tx] = v;
  }
  __syncthreads();
#pragma unroll
  for (int i = 0; i < 4; ++i) {
    int orow = ty + i * 8;
    ((u16*)jb.out)[(c0 + orow) * jb.rows + r0 + tx] = f2bf(tile[tx][orow]);
  }
}

// ---- 64x64-tile GEMM, double-buffered, swizzled LDS ----
// C(M,N) = alpha * A(M,K) @ Bt(N,K)^T, both k-contiguous. 4 waves, each 32x32.
// bf16 operands via global_load_lds(16B); f32 (aflag/bflag) via float4+pack+ds_write.
// LDS chunk swizzle: LDS[row][cl] holds G[row][cl ^ (row&7)] (chunks of 8 elems).
// mode 0: atomicAdd f32 (split-K); 1: store bf16*alpha; 2: store f32*alpha;
// 3: store f32 = addsrc + acc/(count+1e-6).
struct GJob {
  const void* A; const void* Bp; void* C;
  const float* addsrc; const float* cnt;
  long long lda, ldb, ldc, sa_b, sb_b, sc_b, sadd_b;
  float alpha;
  int K, k_chunk, tm, tn, batched, mode, aflag, bflag, nblocks;
};
struct GJobs { GJob j[2]; };

__global__ __launch_bounds__(256, 4) void gemm64(GJobs JJ) {
  __shared__ alignas(16) u16 As[2][64 * 64];
  __shared__ alignas(16) u16 Bs[2][64 * 64];

  int b = blockIdx.x;
  GJob J = JJ.j[0];
  if (b >= J.nblocks) { b -= J.nblocks; J = JJ.j[1]; }

  const int tilesper = J.tm * J.tn;
  const int bz = b / tilesper;
  const int rel = b % tilesper;
  const long long m0 = (long long)(rel / J.tn) * 64;
  const long long n0 = (long long)(rel % J.tn) * 64;

  long long aoff = 0, boff = 0, coff = 0, doff = 0, k0 = 0;
  int Kl = J.K;
  if (J.batched) {
    aoff = (long long)bz * J.sa_b;
    boff = (long long)bz * J.sb_b;
    coff = (long long)bz * J.sc_b;
    doff = (long long)bz * J.sadd_b;
  } else {
    k0 = (long long)bz * J.k_chunk;
    Kl = J.k_chunk;
  }

  const int tid = threadIdx.x;
  const int lane = tid & 63, wave = tid >> 6;
  const int wm = (wave & 1) * 32, wn = (wave >> 1) * 32;
  const int fm = lane & 15, fg = lane >> 4;

  auto stage = [&](u16* dst, const void* src, long long ld, long long off,
                   long long rbase, long long t, int isf32) {
    if (!isf32) {
      const u16* gb = (const u16*)src + off;
#pragma unroll
      for (int j = 0; j < 2; ++j) {
        int cc = wave * 2 + j;
        int row = cc * 8 + (lane >> 3);
        int cg = (lane & 7) ^ (row & 7);
        const u16* g = gb + (rbase + row) * ld + t + cg * 8;
        __builtin_amdgcn_global_load_lds((gas_t)(const void*)g,
                                         (las_t)(void*)(dst + cc * 512 + lane * 8),
                                         16, 0, 0);
      }
    } else {
      const float* gb = (const float*)src + off;
#pragma unroll
      for (int p = 0; p < 2; ++p) {
        int idx = p * 256 + tid;
        int row = idx >> 3, cg = idx & 7;
        const float* g = gb + (rbase + row) * ld + t + cg * 8;
        float4 v0 = *(const float4*)g;
        float4 v1 = *(const float4*)(g + 4);
        *(uint4*)&dst[row * 64 + ((cg ^ (row & 7)) * 8)] = pack8(v0, v1);
      }
    }
  };

  f32x4 acc[2][2];
#pragma unroll
  for (int i = 0; i < 2; ++i)
#pragma unroll
    for (int j = 0; j < 2; ++j) acc[i][j] = (f32x4){0.f, 0.f, 0.f, 0.f};

  const int nIter = Kl >> 6;
  stage(As[0], J.A, J.lda, aoff, m0, k0, J.aflag);
  stage(Bs[0], J.Bp, J.ldb, boff, n0, k0, J.bflag);

  for (int i = 0; i < nIter; ++i) {
    __syncthreads();  // drains current buffer's loads
    if (i + 1 < nIter) {
      long long t = k0 + (long long)(i + 1) * 64;
      stage(As[(i + 1) & 1], J.A, J.lda, aoff, m0, t, J.aflag);
      stage(Bs[(i + 1) & 1], J.Bp, J.ldb, boff, n0, t, J.bflag);
    }
    const u16* Ab = As[i & 1];
    const u16* Bb = Bs[i & 1];
#pragma unroll
    for (int kcc = 0; kcc < 8; kcc += 4) {
      bf16x8 af[2], bf[2];
#pragma unroll
      for (int fi = 0; fi < 2; ++fi) {
        int row = wm + fi * 16 + fm;
        af[fi] = *(const bf16x8*)&Ab[row * 64 + (((kcc + fg) ^ (row & 7)) * 8)];
      }
#pragma unroll
      for (int fj = 0; fj < 2; ++fj) {
        int row = wn + fj * 16 + fm;
        bf[fj] = *(const bf16x8*)&Bb[row * 64 + (((kcc + fg) ^ (row & 7)) * 8)];
      }
#pragma unroll
      for (int fi = 0; fi < 2; ++fi)
#pragma unroll
        for (int fj = 0; fj < 2; ++fj)
          acc[fi][fj] = __builtin_amdgcn_mfma_f32_16x16x32_bf16(af[fi], bf[fj], acc[fi][fj], 0, 0, 0);
    }
  }

  float inv = (J.mode == 3) ? 1.0f / (*J.cnt + 1e-6f) : 0.0f;
#pragma unroll
  for (int fi = 0; fi < 2; ++fi) {
#pragma unroll
    for (int r = 0; r < 4; ++r) {
      long long row = m0 + wm + fi * 16 + fg * 4 + r;
#pragma unroll
      for (int fj = 0; fj < 2; ++fj) {
        long long col = n0 + wn + fj * 16 + fm;
        long long idx = row * J.ldc + col;
        float v = acc[fi][fj][r];
        if (J.mode == 0) {
          atomicAdd((float*)J.C + idx, v * J.alpha);
        } else if (J.mode == 1) {
          ((u16*)J.C)[coff + idx] = f2bf(v * J.alpha);
        } else if (J.mode == 2) {
          ((float*)J.C)[coff + idx] = v * J.alpha;
        } else {
          ((float*)J.C)[coff + idx] = J.addsrc[doff + idx] + v * inv;
        }
      }
    }
  }
}

extern "C" void kernel_launch(void* const* d_in, const int* in_sizes, int n_in,
                              void* d_out, int out_size, void* d_ws, size_t ws_size,
                              hipStream_t stream) {
  (void)in_sizes; (void)n_in; (void)out_size; (void)ws_size;
  const float* zq   = (const float*)d_in[0];
  const float* zs   = (const float*)d_in[1];
  const float* zv   = (const float*)d_in[2];
  const float* conf = (const float*)d_in[3];
  const float* Wk   = (const float*)d_in[4];
  const float* Wv   = (const float*)d_in[5];
  const float* Wo   = (const float*)d_in[6];
  const float* mem  = (const float*)d_in[7];

  float* vret = (float*)d_out;                      // (B, D)
  float* newmem = vret + (long long)B_DIM * D_DIM;  // (H, D, D)

  float* count = (float*)d_ws;
  float* Qf = (float*)((char*)d_ws + 256);               // 1 MB f32 (Q^T, split-K acc)
  float* Sf = (float*)((char*)d_ws + 256 + 1048576);     // 1 MB f32 (S, split-K acc)
  u16* bb   = (u16*)((char*)d_ws + 2097408);
  u16* zsT  = bb;               // 512 x 4096                 [0, 2097152)
  u16* zvlT = bb + 2097152;     // 512 x 4096 (lam-scaled)    [2097152, 4194304)
  u16* WkT  = bb + 4194304;     // 8192 x 512                 [4194304, 8388608)
  u16* WvT  = bb + 8388608;     // 8192 x 512                 [8388608, 12582912)
  u16* WoT  = bb + 12582912;    // 512 x 512                  [12582912, 12845056)
  u16* YTp  = bb + 12845056;    // 512 x 8192 (Y^T)           [12845056, 17039360)
  u16* UT   = bb + 17039360;    // 16 x 512 x 512 (U_h^T)     [17039360, 21233664)

  // D1: transposes + zero(Sf,Qf) + count
  TJobs T;
  T.j[0] = {zs,   zsT,  nullptr, 4096, 512,  16,  0,     0};
  T.j[1] = {zv,   zvlT, conf,    4096, 512,  16,  2048,  1};
  T.j[2] = {Wk,   WkT,  nullptr, 512,  8192, 256, 4096,  0};
  T.j[3] = {Wv,   WvT,  nullptr, 512,  8192, 256, 8192,  0};
  T.j[4] = {Wo,   WoT,  nullptr, 512,  512,  16,  12288, 0};
  T.j[5] = {nullptr, Sf, nullptr, 0, 0, 0,   12544, 4};   // 64 blocks
  T.j[6] = {nullptr, Qf, nullptr, 0, 0, 0,   12608, 4};   // 64 blocks
  T.j[7] = {conf, nullptr, nullptr, 0, 0, 0, 12672, 2};   // 1 block
  T.j[8] = {nullptr, nullptr, nullptr, 0, 0, 0, 0x7FFFFFFF, 0};
  T.j[9] = {nullptr, nullptr, nullptr, 0, 0, 0, 0x7FFFFFFF, 0};
  mega_prep<<<12673, 256, 0, stream>>>(T, count);

  // D2: YT = WoT @ Mflat^T (mem read as f32; 512x8192 out, bf16)
  //   + Sf = zsT @ zvlT^T (split-K 8, f32 atomics)
  GJobs D2;
  D2.j[0] = {WoT, mem, YTp, nullptr, nullptr,
             512, 512, 8192, 0, 0, 0, 0,
             1.0f, 512, 512, 8, 128, 0, 1, 0, 1, 1024};
  D2.j[1] = {zsT, zvlT, Sf, nullptr, nullptr,
             4096, 4096, 512, 0, 0, 0, 0,
             1.0f, 4096, 512, 8, 8, 0, 0, 0, 0, 512};
  gemm64<<<1536, 256, 0, stream>>>(D2);

  // D3: UT_h = WvT_h @ Sf^T (batched 16, bf16 out)
  //   + Qf = YT @ Wk^T (Wk read as f32; K=8192 split-K 8, f32 atomics)
  GJobs D3;
  D3.j[0] = {WvT, Sf, UT, nullptr, nullptr,
             512, 512, 512, 262144, 0, 262144, 0,
             1.0f, 512, 512, 8, 8, 1, 1, 0, 1, 1024};
  D3.j[1] = {YTp, Wk, Qf, nullptr, nullptr,
             8192, 8192, 512, 0, 0, 0, 0,
             1.0f, 8192, 1024, 8, 8, 0, 0, 0, 1, 512};
  gemm64<<<1536, 256, 0, stream>>>(D3);

  // D4: newmem_h = mem_h + (WkT_h @ UT_h^T)/(count+1e-6) (batched 16)
  //   + vret = (1/16) * zq @ Q (zq, Qf read as f32)
  GJobs D4;
  D4.j[0] = {WkT, UT, newmem, mem, count,
             512, 512, 512, 262144, 262144, 262144, 262144,
             1.0f, 512, 512, 8, 8, 1, 3, 0, 0, 1024};
  D4.j[1] = {zq, Qf, vret, nullptr, nullptr,
             512, 512, 512, 0, 0, 0, 0,
             1.0f / 16.0f, 512, 512, 64, 8, 0, 2, 1, 1, 512};
  gemm64<<<1536, 256, 0, stream>>>(D4);
}